// Round 13
// baseline (125.267 us; speedup 1.0000x reference)
//
#include <hip/hip_runtime.h>
#include <stdint.h>

typedef __attribute__((ext_vector_type(8))) short bf16x8;
typedef __attribute__((ext_vector_type(4))) short s16x4;
typedef __attribute__((ext_vector_type(4))) float f32x4;
typedef __attribute__((ext_vector_type(4))) unsigned int u32x4;

#define DEV __device__ __forceinline__

DEV unsigned short f2bf(float f) {
    unsigned u = __builtin_bit_cast(unsigned, f);
    u += 0x7FFFu + ((u >> 16) & 1u);
    return (unsigned short)(u >> 16);
}

DEV void gload_lds16(const void* g, void* l) {
    __builtin_amdgcn_global_load_lds(
        (const __attribute__((address_space(1))) unsigned int*)g,
        (__attribute__((address_space(3))) unsigned int*)l,
        16, 0, 0);
}

// ---------------- elementwise f32 -> bf16 ----------------
__global__ __launch_bounds__(256) void cvt_f32_bf16(
    const float* __restrict__ in, unsigned short* __restrict__ out, int n4) {
    int i = blockIdx.x * blockDim.x + threadIdx.x;
    if (i >= n4) return;
    const float4 v = reinterpret_cast<const float4*>(in)[i];
    s16x4 o;
    o.x = (short)f2bf(v.x); o.y = (short)f2bf(v.y);
    o.z = (short)f2bf(v.z); o.w = (short)f2bf(v.w);
    reinterpret_cast<s16x4*>(out)[i] = o;
}

// ---------------- transpose f32 [K][N] -> bf16 [N][K] ----------------
__global__ __launch_bounds__(256) void transpose_w(
    const float* __restrict__ w, unsigned short* __restrict__ wt, int K, int N) {
    __shared__ unsigned short tile[64][72];
    const int k0 = blockIdx.y * 64, n0 = blockIdx.x * 64;
    const int t = threadIdx.x;
    #pragma unroll
    for (int i = 0; i < 4; ++i) {
        const int e = t + i * 256;
        const int r = e >> 4, c4 = e & 15;
        const float4 v = *reinterpret_cast<const float4*>(w + (size_t)(k0 + r) * N + n0 + c4 * 4);
        s16x4 o;
        o.x = (short)f2bf(v.x); o.y = (short)f2bf(v.y);
        o.z = (short)f2bf(v.z); o.w = (short)f2bf(v.w);
        *(s16x4*)&tile[r][c4 * 4] = o;
    }
    __syncthreads();
    #pragma unroll
    for (int i = 0; i < 4; ++i) {
        const int e = t + i * 256;
        const int rn = e >> 4, c4 = e & 15;
        s16x4 o;
        o.x = (short)tile[c4 * 4 + 0][rn];
        o.y = (short)tile[c4 * 4 + 1][rn];
        o.z = (short)tile[c4 * 4 + 2][rn];
        o.w = (short)tile[c4 * 4 + 3][rn];
        *(s16x4*)(wt + (size_t)(n0 + rn) * K + k0 + c4 * 4) = o;
    }
}

// ======== 8-phase 256x256 GEMM (QKV): C = A[4096x1024] * BT[3072x1024]^T ========
// V is written TRANSPOSED + slot-permuted: vt[(bh*64+d)*2048 + (nn&~63)|perm(nn&63)]
// where perm(k) = (k5,k3,k2,k4,k1,k0) — the PV k-slot convention proven in R7.
__global__ __launch_bounds__(512, 2)
void gemm256_qkv(const unsigned short* __restrict__ A,
                 const unsigned short* __restrict__ BT,
                 const float* __restrict__ bias,
                 unsigned short* __restrict__ q_out,
                 unsigned short* __restrict__ k_out,
                 unsigned short* __restrict__ v_out)
{
    constexpr int K = 1024;
    constexpr int NT = 16;                       // K / 64
    __shared__ unsigned short lds[2][2][2][2][128][32];

    const int t = threadIdx.x;
    const int wave = t >> 6, lane = t & 63;
    const int l15 = lane & 15, l4 = lane >> 4;
    const int wr = wave >> 2, wc = wave & 3;     // 2 M-halves x 4 N-quarters

    // bijective XCD swizzle over 192 blocks (192 % 8 == 0)
    const int lin = blockIdx.x;
    const int logical = (lin & 7) * 24 + (lin >> 3);
    const int bx = logical % 12, by = logical / 12;
    const int tile_m = by * 256, tile_n = bx * 256;

    const int st_row = t >> 2;                               // 0..127
    const int st_col = ((t & 3) ^ ((t >> 3) & 3)) * 8;       // pre-swizzled source col
    const int cswz   = (l4 ^ ((l15 >> 1) & 3)) * 8;          // swizzled read col

    f32x4 acc[8][4] = {};
    bf16x8 ra[4], rb[4];

    #define STAGE(buf, ab, half, kk, k0)                                           \
        gload_lds16(((ab) ? BT : A) +                                              \
                        (size_t)(((ab) ? tile_n : tile_m) + (half) * 128 + st_row) * K \
                        + (k0) + (kk) * 32 + st_col,                               \
                    &lds[buf][ab][half][kk][0][0] + wave * 512)
    #define READ_A(buf, kk, mq)                                                    \
        _Pragma("unroll") for (int i = 0; i < 4; ++i)                              \
            ra[i] = *(const bf16x8*)&lds[buf][0][wr][kk][((mq) * 4 + i) * 16 + l15][cswz];
    #define READ_B(buf, kk)                                                        \
        _Pragma("unroll") for (int n = 0; n < 4; ++n)                              \
            rb[n] = *(const bf16x8*)&lds[buf][1][wc >> 1][kk][(wc & 1) * 64 + n * 16 + l15][cswz];
    #define MFMA16(mq)                                                             \
        __builtin_amdgcn_s_setprio(1);                                             \
        _Pragma("unroll") for (int i = 0; i < 4; ++i)                              \
            _Pragma("unroll") for (int n = 0; n < 4; ++n)                          \
                acc[(mq) * 4 + i][n] = __builtin_amdgcn_mfma_f32_16x16x32_bf16(    \
                    ra[i], rb[n], acc[(mq) * 4 + i][n], 0, 0, 0);                  \
        __builtin_amdgcn_s_setprio(0);
    #define BAR()   __builtin_amdgcn_s_barrier()
    #define LGKM0() do { asm volatile("s_waitcnt lgkmcnt(0)" ::: "memory");        \
                         __builtin_amdgcn_sched_barrier(0); } while (0)

    STAGE(0, 1, 0, 0, 0);  STAGE(0, 1, 1, 0, 0);
    STAGE(0, 0, 0, 0, 0);  STAGE(0, 0, 1, 0, 0);
    STAGE(0, 1, 0, 1, 0);  STAGE(0, 1, 1, 1, 0);
    STAGE(0, 0, 0, 1, 0);  STAGE(0, 0, 1, 1, 0);
    STAGE(1, 1, 0, 0, 64); STAGE(1, 1, 1, 0, 64);
    STAGE(1, 0, 0, 0, 64); STAGE(1, 0, 1, 0, 64);
    STAGE(1, 1, 0, 1, 64); STAGE(1, 1, 1, 1, 64);
    asm volatile("s_waitcnt vmcnt(6)" ::: "memory");
    BAR();

    for (int kt = 0; kt < NT; ++kt) {
        const int buf = kt & 1;
        const int k0 = kt * 64;
        const bool s1 = (kt + 1 < NT);
        const bool s234 = (kt + 2 < NT);

        READ_A(buf, 0, 0); READ_B(buf, 0);
        if (s1) { STAGE(buf ^ 1, 0, 0, 1, k0 + 64); STAGE(buf ^ 1, 0, 1, 1, k0 + 64); }
        BAR(); LGKM0();
        MFMA16(0);
        BAR();

        READ_A(buf, 0, 1);
        if (s234) { STAGE(buf, 1, 0, 0, k0 + 128); STAGE(buf, 1, 1, 0, k0 + 128); }
        BAR(); LGKM0();
        MFMA16(1);
        BAR();

        READ_A(buf, 1, 0); READ_B(buf, 1);
        if (s234) { STAGE(buf, 0, 0, 0, k0 + 128); STAGE(buf, 0, 1, 0, k0 + 128); }
        BAR(); LGKM0();
        MFMA16(0);
        BAR();

        READ_A(buf, 1, 1);
        if (s234) { STAGE(buf, 1, 0, 1, k0 + 128); STAGE(buf, 1, 1, 1, k0 + 128); }
        BAR(); LGKM0();
        MFMA16(1);
        if (kt < NT - 2)       asm volatile("s_waitcnt vmcnt(6)" ::: "memory");
        else if (kt == NT - 2) asm volatile("s_waitcnt vmcnt(0)" ::: "memory");
        if (kt < NT - 1) BAR();
    }
    #undef STAGE
    #undef READ_A
    #undef READ_B
    #undef MFMA16
    #undef BAR
    #undef LGKM0

    float bcol[4];
    #pragma unroll
    for (int n = 0; n < 4; ++n) bcol[n] = bias[tile_n + wc * 64 + n * 16 + l15];

    #pragma unroll
    for (int m = 0; m < 8; ++m)
        #pragma unroll
        for (int n = 0; n < 4; ++n) {
            const int col = tile_n + wc * 64 + n * 16 + l15;
            const int which = col >> 10;
            const int hh = (col >> 6) & 15;
            const int d = col & 63;
            const int row0 = tile_m + wr * 128 + m * 16 + l4 * 4;
            const int bb = row0 >> 11, nn = row0 & 2047;
            if (which == 2) {
                // V^T, slot-permuted keys; r = low 2 bits preserved -> packed store
                const int nl = nn & 63;
                const int np = (nl & 32) | ((nl & 12) << 1) | ((nl & 16) >> 2) | (nl & 3);
                const size_t dstV = ((size_t)((bb * 16 + hh) * 64 + d)) * 2048 + (nn & ~63) + np;
                s16x4 pk;
                #pragma unroll
                for (int r = 0; r < 4; ++r) pk[r] = (short)f2bf(acc[m][n][r] + bcol[n]);
                *(s16x4*)&v_out[dstV] = pk;
            } else {
                #pragma unroll
                for (int r = 0; r < 4; ++r) {
                    const float v = acc[m][n][r] + bcol[n];
                    const size_t dst = ((size_t)((bb * 16 + hh) * 2048 + nn + r)) * 64 + d;
                    // Q pre-scale = 1/sqrt(64); softmax in NATURAL-log domain
                    if (which == 0) q_out[dst] = f2bf(v * 0.125f);
                    else            k_out[dst] = f2bf(v);
                }
            }
        }
}

// ---------------- proj GEMM (128x64 tiles, 512 blocks = 2/CU): f32 out ----------
// Same staging/fragment math as the proven 128^2 kernel; per-wave output 32x64
// (acc[2][4]); B tile is 64 rows. Grid (16,32) doubles waves/SIMD vs the old
// 128^2 proj (256 blocks = 1 block/CU = 1 wave/SIMD).
__global__ __launch_bounds__(256)
void gemm_proj(const unsigned short* __restrict__ A,
               const unsigned short* __restrict__ BT,
               const float* __restrict__ bias,
               float* __restrict__ f_out)
{
    constexpr int K = 1024, N = 1024;
    __shared__ unsigned short Abuf[128 * 64];
    __shared__ unsigned short Bbuf[64 * 64];

    const int t = threadIdx.x;
    const int wave = t >> 6, lane = t & 63;
    const int l15 = lane & 15, l4 = lane >> 4;
    const int tile_n = blockIdx.x * 64, tile_m = blockIdx.y * 128;

    const int srow = wave * 32 + (lane >> 3);   // A staging rows (+c*8)
    const int brow = t >> 3;                    // B staging rows (+c*32)
    const int scol = (lane & 7) * 8;

    f32x4 acc[2][4] = {};

    for (int kt = 0; kt < 16; ++kt) {
        const int k0 = kt << 6;
        __syncthreads();
        #pragma unroll
        for (int c = 0; c < 4; ++c)
            gload_lds16(A + (size_t)(tile_m + srow + c * 8) * K + k0 + scol,
                        &Abuf[(wave * 32 + c * 8) * 64]);
        #pragma unroll
        for (int c = 0; c < 2; ++c)
            gload_lds16(BT + (size_t)(tile_n + brow + c * 32) * K + k0 + scol,
                        &Bbuf[(c * 32 + wave * 8) * 64]);
        asm volatile("s_waitcnt vmcnt(0)" ::: "memory");
        __syncthreads();

        bf16x8 ra[2][2], rb[4][2];
        #pragma unroll
        for (int m = 0; m < 2; ++m)
            #pragma unroll
            for (int ks = 0; ks < 2; ++ks)
                ra[m][ks] = *(const bf16x8*)&Abuf[(wave * 32 + m * 16 + l15) * 64 + ks * 32 + l4 * 8];
        #pragma unroll
        for (int n = 0; n < 4; ++n)
            #pragma unroll
            for (int ks = 0; ks < 2; ++ks)
                rb[n][ks] = *(const bf16x8*)&Bbuf[(n * 16 + l15) * 64 + ks * 32 + l4 * 8];

        #pragma unroll
        for (int m = 0; m < 2; ++m)
            #pragma unroll
            for (int n = 0; n < 4; ++n) {
                acc[m][n] = __builtin_amdgcn_mfma_f32_16x16x32_bf16(ra[m][0], rb[n][0], acc[m][n], 0, 0, 0);
                acc[m][n] = __builtin_amdgcn_mfma_f32_16x16x32_bf16(ra[m][1], rb[n][1], acc[m][n], 0, 0, 0);
            }
    }

    float bcol[4];
    #pragma unroll
    for (int n = 0; n < 4; ++n) bcol[n] = bias[tile_n + n * 16 + l15];

    #pragma unroll
    for (int m = 0; m < 2; ++m)
        #pragma unroll
        for (int n = 0; n < 4; ++n) {
            const int col = tile_n + n * 16 + l15;
            #pragma unroll
            for (int r = 0; r < 4; ++r) {
                const int row = tile_m + wave * 32 + m * 16 + l4 * 4 + r;
                f_out[(size_t)row * N + col] = acc[m][n][r] + bcol[n];
            }
        }
}

// ---------------- fused flash attention (v12: 2 tiles per barrier window) -----------
// Single change vs passing v11 structure: loop steps 2 tiles per iter. Per iter:
// vmcnt(0) (waits only own 2 loads, issued a full compute-phase earlier — near-free)
// -> s_barrier (publishes all waves' loads; also proves all waves finished
// compute(kt-2,kt-1)) -> issue loads for tiles kt+2,kt+3 into those freed buffers
// (issue is AFTER the barrier, so no overwrite race) -> compute tiles kt,kt+1 as
// two INDEPENDENT chains in one region: tile B's QK MFMAs fill tile A's exp/pack
// bubbles and vice versa (the binding constraint per R10-R12 nulls).
__global__ __launch_bounds__(1024, 8)
void attn_kernel(const unsigned short* __restrict__ Qb,
                 const unsigned short* __restrict__ Kb,
                 const unsigned short* __restrict__ Vt,
                 const float* __restrict__ bias,
                 unsigned short* __restrict__ Ob)
{
    __shared__ __align__(16) unsigned char pool[73728];
    unsigned short (*Kf)[4096] = (unsigned short (*)[4096])(pool);          // [4][64*64]
    unsigned short (*Vf)[4096] = (unsigned short (*)[4096])(pool + 32768);  // [4][64*64]
    float* blds = (float*)(pool + 65536);                                   // 8192 B
    // epilogue overlays (K/V dead by then):
    float (*Oscr)[16][64] = (float (*)[16][64])(pool);                      // 32768 B
    float (*Lscr)[8][16]  = (float (*)[8][16])(pool + 32768);               //  1024 B

    const unsigned di = blockIdx.x;
    const unsigned logical = (di & 7) * 64 + (di >> 3);
    const int qt = logical & 15;
    const int h  = (logical >> 4) & 15;
    const int b  = logical >> 8;

    const int t = threadIdx.x;
    const int wave = t >> 6, lane = t & 63;
    const int l15 = lane & 15, l4 = lane >> 4;
    const int wq = wave >> 1, wk = wave & 1;      // 8 q-groups x 2 key-halves
    const int kb0 = wk * 32;
    const int xsw = (l15 & 7) << 3;               // read-side XOR (elems)

    const size_t head = ((size_t)(b * 16 + h)) * 2048 * 64;
    const unsigned short* Qh = Qb + head;
    const unsigned short* Kh = Kb + head;

    // staging roles: waves 0-7 cover K rows, waves 8-15 cover V^T d-rows; 1 load/tile
    const int w8 = wave & 7;
    const int srow8 = w8 * 8 + (lane >> 3);
    const int scol8 = 8 * ((lane & 7) ^ (lane >> 3));
    const unsigned short* Src = (wave < 8)
        ? Kh + (size_t)srow8 * 64 + scol8
        : Vt + ((size_t)((b * 16 + h) * 64) + srow8) * 2048 + scol8;
    const int sstep = (wave < 8) ? 64 * 64 : 64;  // per-tile advance (K rows vs V cols)
    unsigned short* lbase = (wave < 8) ? &Kf[0][w8 * 512] : &Vf[0][w8 * 512];

    for (int i = t; i < 2048; i += 1024) blds[i] = bias[b * 2048 + i] - 5.5451774f;

    const int qbase = qt * 128 + wq * 16;
    bf16x8 qf[2];
    #pragma unroll
    for (int ks = 0; ks < 2; ++ks)
        qf[ks] = *(const bf16x8*)(Qh + (size_t)(qbase + l15) * 64 + ks * 32 + l4 * 8);

    float lsum = 0.f;
    f32x4 oacc[4] = {};

    // prologue: stage tiles 0,1; one-time full drain (also publishes blds)
    gload_lds16(Src, lbase);
    gload_lds16(Src + sstep, lbase + 4096);
    __syncthreads();

    for (int kt = 0; kt < 32; kt += 2) {
        // own tiles kt,kt+1 are the only outstanding loads; they had a full
        // 2-tile compute phase to fly -> this wait is near-free
        asm volatile("s_waitcnt vmcnt(0)" ::: "memory");
        __builtin_amdgcn_s_barrier();            // publish all waves' loads
        __builtin_amdgcn_sched_barrier(0);       // keep ds_reads below the barrier

        // prefetch next pair into buffers freed by compute(kt-2,kt-1) — all waves
        // provably past that compute (they crossed this barrier)
        if (kt < 30) {
            gload_lds16(Src + (size_t)(kt + 2) * sstep, lbase + ((kt + 2) & 3) * 4096);
            gload_lds16(Src + (size_t)(kt + 3) * sstep, lbase + ((kt + 3) & 3) * 4096);
        }

        #pragma unroll
        for (int u = 0; u < 2; ++u) {
            const int tb = (kt + u) & 3;
            const int key0 = (kt + u) * 64;
            const unsigned short* Kp = Kf[tb];
            const unsigned short* Vp = Vf[tb];

            bf16x8 kfr[2][2];
            #pragma unroll
            for (int f = 0; f < 2; ++f)
                #pragma unroll
                for (int ks = 0; ks < 2; ++ks)
                    kfr[f][ks] = *(const bf16x8*)&Kp[(kb0 + f * 16 + l15) * 64 + ((ks * 32 + l4 * 8) ^ xsw)];

            f32x4 bk[2];
            #pragma unroll
            for (int f = 0; f < 2; ++f)
                bk[f] = *(const f32x4*)&blds[key0 + kb0 + f * 16 + l4 * 4];

            f32x4 s[2];
            #pragma unroll
            for (int f = 0; f < 2; ++f) {
                f32x4 z = bk[f];
                z = __builtin_amdgcn_mfma_f32_16x16x32_bf16(kfr[f][0], qf[0], z, 0, 0, 0);
                z = __builtin_amdgcn_mfma_f32_16x16x32_bf16(kfr[f][1], qf[1], z, 0, 0, 0);
                s[f] = z;
            }

            float ps = 0.f;
            u32x4 w;
            #pragma unroll
            for (int f = 0; f < 2; ++f) {
                const float p0 = __expf(s[f][0]);
                const float p1 = __expf(s[f][1]);
                const float p2 = __expf(s[f][2]);
                const float p3 = __expf(s[f][3]);
                ps += (p0 + p1) + (p2 + p3);
                unsigned w0, w1;
                asm("v_cvt_pk_bf16_f32 %0, %1, %2" : "=v"(w0) : "v"(p0), "v"(p1));
                asm("v_cvt_pk_bf16_f32 %0, %1, %2" : "=v"(w1) : "v"(p2), "v"(p3));
                w[f * 2] = w0; w[f * 2 + 1] = w1;
            }
            lsum += ps;
            const bf16x8 pa = __builtin_bit_cast(bf16x8, w);

            #pragma unroll
            for (int df = 0; df < 4; ++df) {
                bf16x8 vf = *(const bf16x8*)&Vp[(df * 16 + l15) * 64 + ((kb0 + l4 * 8) ^ xsw)];
                oacc[df] = __builtin_amdgcn_mfma_f32_16x16x32_bf16(pa, vf, oacc[df], 0, 0, 0);
            }
        }
    }

    lsum += __shfl_xor(lsum, 16, 64);
    lsum += __shfl_xor(lsum, 32, 64);

    __syncthreads();
    if (lane < 16) Lscr[wk][wq][lane] = lsum;
    if (wk == 1) {
        #pragma unroll
        for (int df = 0; df < 4; ++df)
            #pragma unroll
            for (int r = 0; r < 4; ++r)
                Oscr[wq][l4 * 4 + r][df * 16 + l15] = oacc[df][r];
    }
    __syncthreads();
    if (wk == 0) {
        float inv[4];
        #pragma unroll
        for (int r = 0; r < 4; ++r) {
            const int ql = l4 * 4 + r;
            inv[r] = 1.0f / (Lscr[0][wq][ql] + Lscr[1][wq][ql]);
        }
        #pragma unroll
        for (int r = 0; r < 4; ++r) {
            const int ql = l4 * 4 + r;
            const int q = qbase + ql;
            #pragma unroll
            for (int df = 0; df < 4; ++df) {
                const int d = df * 16 + l15;
                const float v = oacc[df][r] + Oscr[wq][ql][d];
                Ob[((size_t)(b * 2048 + q)) * 1024 + h * 64 + d] = f2bf(v * inv[r]);
            }
        }
    }
}

// ---------------- launch ----------------
extern "C" void kernel_launch(void* const* d_in, const int* in_sizes, int n_in,
                              void* d_out, int out_size, void* d_ws, size_t ws_size,
                              hipStream_t stream) {
    const float* x      = (const float*)d_in[0];
    const float* abias  = (const float*)d_in[1];
    const float* w_qkv  = (const float*)d_in[2];
    const float* b_qkv  = (const float*)d_in[3];
    const float* w_proj = (const float*)d_in[4];
    const float* b_proj = (const float*)d_in[5];
    float* out = (float*)d_out;

    unsigned short* ws = (unsigned short*)d_ws;
    unsigned short* xb  = ws;                                  // 4096*1024
    unsigned short* wqT = xb  + (size_t)4096 * 1024;           // 3072*1024
    unsigned short* wpT = wqT + (size_t)3072 * 1024;           // 1024*1024
    unsigned short* qb  = wpT + (size_t)1024 * 1024;           // 2*16*2048*64
    unsigned short* kb  = qb  + (size_t)2 * 16 * 2048 * 64;
    unsigned short* vt  = kb  + (size_t)2 * 16 * 2048 * 64;    // V^T perm'd
    unsigned short* ao  = vt  + (size_t)2 * 16 * 2048 * 64;    // 4096*1024

    cvt_f32_bf16<<<4096, 256, 0, stream>>>(x, xb, 1048576);
    transpose_w<<<dim3(48, 16), 256, 0, stream>>>(w_qkv, wqT, 1024, 3072);
    transpose_w<<<dim3(16, 16), 256, 0, stream>>>(w_proj, wpT, 1024, 1024);
    gemm256_qkv<<<192, 512, 0, stream>>>(xb, wqT, b_qkv, qb, kb, vt);
    attn_kernel<<<512, 1024, 0, stream>>>(qb, kb, vt, abias, ao);
    gemm_proj<<<dim3(16, 32), 256, 0, stream>>>(ao, wpT, b_proj, out);
}

// Round 14
// 115.584 us; speedup vs baseline: 1.0838x; 1.0838x over previous
//
#include <hip/hip_runtime.h>
#include <stdint.h>

typedef __attribute__((ext_vector_type(8))) short bf16x8;
typedef __attribute__((ext_vector_type(4))) short s16x4;
typedef __attribute__((ext_vector_type(4))) float f32x4;
typedef __attribute__((ext_vector_type(4))) unsigned int u32x4;

#define DEV __device__ __forceinline__

DEV unsigned short f2bf(float f) {
    unsigned u = __builtin_bit_cast(unsigned, f);
    u += 0x7FFFu + ((u >> 16) & 1u);
    return (unsigned short)(u >> 16);
}

DEV void gload_lds16(const void* g, void* l) {
    __builtin_amdgcn_global_load_lds(
        (const __attribute__((address_space(1))) unsigned int*)g,
        (__attribute__((address_space(3))) unsigned int*)l,
        16, 0, 0);
}

// ---------------- elementwise f32 -> bf16 ----------------
__global__ __launch_bounds__(256) void cvt_f32_bf16(
    const float* __restrict__ in, unsigned short* __restrict__ out, int n4) {
    int i = blockIdx.x * blockDim.x + threadIdx.x;
    if (i >= n4) return;
    const float4 v = reinterpret_cast<const float4*>(in)[i];
    s16x4 o;
    o.x = (short)f2bf(v.x); o.y = (short)f2bf(v.y);
    o.z = (short)f2bf(v.z); o.w = (short)f2bf(v.w);
    reinterpret_cast<s16x4*>(out)[i] = o;
}

// ---------------- transpose f32 [K][N] -> bf16 [N][K] ----------------
__global__ __launch_bounds__(256) void transpose_w(
    const float* __restrict__ w, unsigned short* __restrict__ wt, int K, int N) {
    __shared__ unsigned short tile[64][72];
    const int k0 = blockIdx.y * 64, n0 = blockIdx.x * 64;
    const int t = threadIdx.x;
    #pragma unroll
    for (int i = 0; i < 4; ++i) {
        const int e = t + i * 256;
        const int r = e >> 4, c4 = e & 15;
        const float4 v = *reinterpret_cast<const float4*>(w + (size_t)(k0 + r) * N + n0 + c4 * 4);
        s16x4 o;
        o.x = (short)f2bf(v.x); o.y = (short)f2bf(v.y);
        o.z = (short)f2bf(v.z); o.w = (short)f2bf(v.w);
        *(s16x4*)&tile[r][c4 * 4] = o;
    }
    __syncthreads();
    #pragma unroll
    for (int i = 0; i < 4; ++i) {
        const int e = t + i * 256;
        const int rn = e >> 4, c4 = e & 15;
        s16x4 o;
        o.x = (short)tile[c4 * 4 + 0][rn];
        o.y = (short)tile[c4 * 4 + 1][rn];
        o.z = (short)tile[c4 * 4 + 2][rn];
        o.w = (short)tile[c4 * 4 + 3][rn];
        *(s16x4*)(wt + (size_t)(n0 + rn) * K + k0 + c4 * 4) = o;
    }
}

// ======== 8-phase 256x256 GEMM (QKV): C = A[4096x1024] * BT[3072x1024]^T ========
// V is written TRANSPOSED + slot-permuted: vt[(bh*64+d)*2048 + (nn&~63)|perm(nn&63)]
// where perm(k) = (k5,k3,k2,k4,k1,k0) — the PV k-slot convention proven in R7.
__global__ __launch_bounds__(512, 2)
void gemm256_qkv(const unsigned short* __restrict__ A,
                 const unsigned short* __restrict__ BT,
                 const float* __restrict__ bias,
                 unsigned short* __restrict__ q_out,
                 unsigned short* __restrict__ k_out,
                 unsigned short* __restrict__ v_out)
{
    constexpr int K = 1024;
    constexpr int NT = 16;                       // K / 64
    __shared__ unsigned short lds[2][2][2][2][128][32];

    const int t = threadIdx.x;
    const int wave = t >> 6, lane = t & 63;
    const int l15 = lane & 15, l4 = lane >> 4;
    const int wr = wave >> 2, wc = wave & 3;     // 2 M-halves x 4 N-quarters

    // bijective XCD swizzle over 192 blocks (192 % 8 == 0)
    const int lin = blockIdx.x;
    const int logical = (lin & 7) * 24 + (lin >> 3);
    const int bx = logical % 12, by = logical / 12;
    const int tile_m = by * 256, tile_n = bx * 256;

    const int st_row = t >> 2;                               // 0..127
    const int st_col = ((t & 3) ^ ((t >> 3) & 3)) * 8;       // pre-swizzled source col
    const int cswz   = (l4 ^ ((l15 >> 1) & 3)) * 8;          // swizzled read col

    f32x4 acc[8][4] = {};
    bf16x8 ra[4], rb[4];

    #define STAGE(buf, ab, half, kk, k0)                                           \
        gload_lds16(((ab) ? BT : A) +                                              \
                        (size_t)(((ab) ? tile_n : tile_m) + (half) * 128 + st_row) * K \
                        + (k0) + (kk) * 32 + st_col,                               \
                    &lds[buf][ab][half][kk][0][0] + wave * 512)
    #define READ_A(buf, kk, mq)                                                    \
        _Pragma("unroll") for (int i = 0; i < 4; ++i)                              \
            ra[i] = *(const bf16x8*)&lds[buf][0][wr][kk][((mq) * 4 + i) * 16 + l15][cswz];
    #define READ_B(buf, kk)                                                        \
        _Pragma("unroll") for (int n = 0; n < 4; ++n)                              \
            rb[n] = *(const bf16x8*)&lds[buf][1][wc >> 1][kk][(wc & 1) * 64 + n * 16 + l15][cswz];
    #define MFMA16(mq)                                                             \
        __builtin_amdgcn_s_setprio(1);                                             \
        _Pragma("unroll") for (int i = 0; i < 4; ++i)                              \
            _Pragma("unroll") for (int n = 0; n < 4; ++n)                          \
                acc[(mq) * 4 + i][n] = __builtin_amdgcn_mfma_f32_16x16x32_bf16(    \
                    ra[i], rb[n], acc[(mq) * 4 + i][n], 0, 0, 0);                  \
        __builtin_amdgcn_s_setprio(0);
    #define BAR()   __builtin_amdgcn_s_barrier()
    #define LGKM0() do { asm volatile("s_waitcnt lgkmcnt(0)" ::: "memory");        \
                         __builtin_amdgcn_sched_barrier(0); } while (0)

    STAGE(0, 1, 0, 0, 0);  STAGE(0, 1, 1, 0, 0);
    STAGE(0, 0, 0, 0, 0);  STAGE(0, 0, 1, 0, 0);
    STAGE(0, 1, 0, 1, 0);  STAGE(0, 1, 1, 1, 0);
    STAGE(0, 0, 0, 1, 0);  STAGE(0, 0, 1, 1, 0);
    STAGE(1, 1, 0, 0, 64); STAGE(1, 1, 1, 0, 64);
    STAGE(1, 0, 0, 0, 64); STAGE(1, 0, 1, 0, 64);
    STAGE(1, 1, 0, 1, 64); STAGE(1, 1, 1, 1, 64);
    asm volatile("s_waitcnt vmcnt(6)" ::: "memory");
    BAR();

    for (int kt = 0; kt < NT; ++kt) {
        const int buf = kt & 1;
        const int k0 = kt * 64;
        const bool s1 = (kt + 1 < NT);
        const bool s234 = (kt + 2 < NT);

        READ_A(buf, 0, 0); READ_B(buf, 0);
        if (s1) { STAGE(buf ^ 1, 0, 0, 1, k0 + 64); STAGE(buf ^ 1, 0, 1, 1, k0 + 64); }
        BAR(); LGKM0();
        MFMA16(0);
        BAR();

        READ_A(buf, 0, 1);
        if (s234) { STAGE(buf, 1, 0, 0, k0 + 128); STAGE(buf, 1, 1, 0, k0 + 128); }
        BAR(); LGKM0();
        MFMA16(1);
        BAR();

        READ_A(buf, 1, 0); READ_B(buf, 1);
        if (s234) { STAGE(buf, 0, 0, 0, k0 + 128); STAGE(buf, 0, 1, 0, k0 + 128); }
        BAR(); LGKM0();
        MFMA16(0);
        BAR();

        READ_A(buf, 1, 1);
        if (s234) { STAGE(buf, 1, 0, 1, k0 + 128); STAGE(buf, 1, 1, 1, k0 + 128); }
        BAR(); LGKM0();
        MFMA16(1);
        if (kt < NT - 2)       asm volatile("s_waitcnt vmcnt(6)" ::: "memory");
        else if (kt == NT - 2) asm volatile("s_waitcnt vmcnt(0)" ::: "memory");
        if (kt < NT - 1) BAR();
    }
    #undef STAGE
    #undef READ_A
    #undef READ_B
    #undef MFMA16
    #undef BAR
    #undef LGKM0

    float bcol[4];
    #pragma unroll
    for (int n = 0; n < 4; ++n) bcol[n] = bias[tile_n + wc * 64 + n * 16 + l15];

    #pragma unroll
    for (int m = 0; m < 8; ++m)
        #pragma unroll
        for (int n = 0; n < 4; ++n) {
            const int col = tile_n + wc * 64 + n * 16 + l15;
            const int which = col >> 10;
            const int hh = (col >> 6) & 15;
            const int d = col & 63;
            const int row0 = tile_m + wr * 128 + m * 16 + l4 * 4;
            const int bb = row0 >> 11, nn = row0 & 2047;
            if (which == 2) {
                // V^T, slot-permuted keys; r = low 2 bits preserved -> packed store
                const int nl = nn & 63;
                const int np = (nl & 32) | ((nl & 12) << 1) | ((nl & 16) >> 2) | (nl & 3);
                const size_t dstV = ((size_t)((bb * 16 + hh) * 64 + d)) * 2048 + (nn & ~63) + np;
                s16x4 pk;
                #pragma unroll
                for (int r = 0; r < 4; ++r) pk[r] = (short)f2bf(acc[m][n][r] + bcol[n]);
                *(s16x4*)&v_out[dstV] = pk;
            } else {
                #pragma unroll
                for (int r = 0; r < 4; ++r) {
                    const float v = acc[m][n][r] + bcol[n];
                    const size_t dst = ((size_t)((bb * 16 + hh) * 2048 + nn + r)) * 64 + d;
                    // Q pre-scale = 1/sqrt(64); softmax in NATURAL-log domain
                    if (which == 0) q_out[dst] = f2bf(v * 0.125f);
                    else            k_out[dst] = f2bf(v);
                }
            }
        }
}

// ---------------- proj GEMM (128x64 tiles, 512 blocks = 2/CU): f32 out ----------
__global__ __launch_bounds__(256)
void gemm_proj(const unsigned short* __restrict__ A,
               const unsigned short* __restrict__ BT,
               const float* __restrict__ bias,
               float* __restrict__ f_out)
{
    constexpr int K = 1024, N = 1024;
    __shared__ unsigned short Abuf[128 * 64];
    __shared__ unsigned short Bbuf[64 * 64];

    const int t = threadIdx.x;
    const int wave = t >> 6, lane = t & 63;
    const int l15 = lane & 15, l4 = lane >> 4;
    const int tile_n = blockIdx.x * 64, tile_m = blockIdx.y * 128;

    const int srow = wave * 32 + (lane >> 3);   // A staging rows (+c*8)
    const int brow = t >> 3;                    // B staging rows (+c*32)
    const int scol = (lane & 7) * 8;

    f32x4 acc[2][4] = {};

    for (int kt = 0; kt < 16; ++kt) {
        const int k0 = kt << 6;
        __syncthreads();
        #pragma unroll
        for (int c = 0; c < 4; ++c)
            gload_lds16(A + (size_t)(tile_m + srow + c * 8) * K + k0 + scol,
                        &Abuf[(wave * 32 + c * 8) * 64]);
        #pragma unroll
        for (int c = 0; c < 2; ++c)
            gload_lds16(BT + (size_t)(tile_n + brow + c * 32) * K + k0 + scol,
                        &Bbuf[(c * 32 + wave * 8) * 64]);
        asm volatile("s_waitcnt vmcnt(0)" ::: "memory");
        __syncthreads();

        bf16x8 ra[2][2], rb[4][2];
        #pragma unroll
        for (int m = 0; m < 2; ++m)
            #pragma unroll
            for (int ks = 0; ks < 2; ++ks)
                ra[m][ks] = *(const bf16x8*)&Abuf[(wave * 32 + m * 16 + l15) * 64 + ks * 32 + l4 * 8];
        #pragma unroll
        for (int n = 0; n < 4; ++n)
            #pragma unroll
            for (int ks = 0; ks < 2; ++ks)
                rb[n][ks] = *(const bf16x8*)&Bbuf[(n * 16 + l15) * 64 + ks * 32 + l4 * 8];

        #pragma unroll
        for (int m = 0; m < 2; ++m)
            #pragma unroll
            for (int n = 0; n < 4; ++n) {
                acc[m][n] = __builtin_amdgcn_mfma_f32_16x16x32_bf16(ra[m][0], rb[n][0], acc[m][n], 0, 0, 0);
                acc[m][n] = __builtin_amdgcn_mfma_f32_16x16x32_bf16(ra[m][1], rb[n][1], acc[m][n], 0, 0, 0);
            }
    }

    float bcol[4];
    #pragma unroll
    for (int n = 0; n < 4; ++n) bcol[n] = bias[tile_n + n * 16 + l15];

    #pragma unroll
    for (int m = 0; m < 2; ++m)
        #pragma unroll
        for (int n = 0; n < 4; ++n) {
            const int col = tile_n + n * 16 + l15;
            #pragma unroll
            for (int r = 0; r < 4; ++r) {
                const int row = tile_m + wave * 32 + m * 16 + l4 * 4 + r;
                f_out[(size_t)row * N + col] = acc[m][n][r] + bcol[n];
            }
        }
}

// ---------------- fused flash attention (v9 — best measured: ~50 us, R10) ----------
// Zero-VALU staging (gload_lds, T21 both-sides swizzle), hw __expf natural-log
// fixed-offset softmax, in-register P via k-slot permutation, double-buffered K/V,
// one __syncthreads per tile. 512 threads: 4 q-groups x 2 key-halves.
__global__ __launch_bounds__(512, 4)
void attn_kernel(const unsigned short* __restrict__ Qb,
                 const unsigned short* __restrict__ Kb,
                 const unsigned short* __restrict__ Vt,
                 const float* __restrict__ bias,
                 unsigned short* __restrict__ Ob)
{
    __shared__ __align__(16) unsigned char pool[40960];
    unsigned short (*Kf)[4096] = (unsigned short (*)[4096])(pool);          // [2][64*64]
    unsigned short (*Vf)[4096] = (unsigned short (*)[4096])(pool + 16384);  // [2][64*64]
    float* blds = (float*)(pool + 32768);                                   // 8192 B
    // epilogue overlays (K/V/bias dead by then):
    float (*Oscr)[32][64] = (float (*)[32][64])(pool);                      // 32768 B
    float (*Lscr)[4][32]  = (float (*)[4][32])(pool + 32768);               //  1024 B

    const unsigned di = blockIdx.x;
    const unsigned logical = (di & 7) * 64 + (di >> 3);
    const int qt = logical & 15;
    const int h  = (logical >> 4) & 15;
    const int b  = logical >> 8;

    const int t = threadIdx.x;
    const int wave = t >> 6, lane = t & 63;
    const int l15 = lane & 15, l4 = lane >> 4;
    const int wq = wave & 3, wk = wave >> 2;
    const int kb0 = wk * 32;
    const int xsw = (l15 & 7) << 3;               // read-side XOR (elems)

    const size_t head = ((size_t)(b * 16 + h)) * 2048 * 64;
    const unsigned short* Qh = Qb + head;
    const unsigned short* Kh = Kb + head;

    // staging: wave w covers 8 rows; per-lane pre-swizzled source column
    const int srow8 = wave * 8 + (lane >> 3);
    const int scol8 = 8 * ((lane & 7) ^ (lane >> 3));
    const unsigned short* Ksrc = Kh + (size_t)srow8 * 64 + scol8;
    const unsigned short* Vsrc = Vt + ((size_t)((b * 16 + h) * 64) + srow8) * 2048 + scol8;

    for (int i = t; i < 2048; i += 512) blds[i] = bias[b * 2048 + i] - 5.5451774f;

    const int qbase = qt * 128 + wq * 32;
    bf16x8 qf[2][2];
    #pragma unroll
    for (int qi = 0; qi < 2; ++qi)
        #pragma unroll
        for (int ks = 0; ks < 2; ++ks)
            qf[qi][ks] = *(const bf16x8*)(Qh + (size_t)(qbase + qi * 16 + l15) * 64 + ks * 32 + l4 * 8);

    float lsum[2] = {0.f, 0.f};
    f32x4 oacc[2][4] = {};

    // prologue: stage tile 0 into buf 0
    gload_lds16(Ksrc, &Kf[0][wave * 512]);
    gload_lds16(Vsrc, &Vf[0][wave * 512]);
    __syncthreads();   // drains vmcnt + lgkm (blds) for all waves

    for (int kt = 0; kt < 32; ++kt) {
        const int key0 = kt * 64;
        const int pb = kt & 1;

        // issue next-tile loads into buf^1 (its last readers were pre-barrier(kt-1))
        if (kt < 31) {
            gload_lds16(Ksrc + (size_t)(key0 + 64) * 64, &Kf[pb ^ 1][wave * 512]);
            gload_lds16(Vsrc + key0 + 64, &Vf[pb ^ 1][wave * 512]);
        }

        const unsigned short* Kp = Kf[pb];
        const unsigned short* Vp = Vf[pb];

        bf16x8 kfr[2][2];
        #pragma unroll
        for (int f = 0; f < 2; ++f)
            #pragma unroll
            for (int ks = 0; ks < 2; ++ks)
                kfr[f][ks] = *(const bf16x8*)&Kp[(kb0 + f * 16 + l15) * 64 + ((ks * 32 + l4 * 8) ^ xsw)];

        f32x4 bk[2];
        #pragma unroll
        for (int f = 0; f < 2; ++f)
            bk[f] = *(const f32x4*)&blds[key0 + kb0 + f * 16 + l4 * 4];

        f32x4 s[2][2];
        __builtin_amdgcn_s_setprio(1);
        #pragma unroll
        for (int qi = 0; qi < 2; ++qi)
            #pragma unroll
            for (int f = 0; f < 2; ++f) {
                f32x4 z = bk[f];
                z = __builtin_amdgcn_mfma_f32_16x16x32_bf16(kfr[f][0], qf[qi][0], z, 0, 0, 0);
                z = __builtin_amdgcn_mfma_f32_16x16x32_bf16(kfr[f][1], qf[qi][1], z, 0, 0, 0);
                s[qi][f] = z;
            }
        __builtin_amdgcn_s_setprio(0);

        bf16x8 pa[2];
        #pragma unroll
        for (int qi = 0; qi < 2; ++qi) {
            float ps = 0.f;
            u32x4 w;
            #pragma unroll
            for (int f = 0; f < 2; ++f) {
                const float p0 = __expf(s[qi][f][0]);
                const float p1 = __expf(s[qi][f][1]);
                const float p2 = __expf(s[qi][f][2]);
                const float p3 = __expf(s[qi][f][3]);
                ps += (p0 + p1) + (p2 + p3);
                unsigned w0, w1;
                asm("v_cvt_pk_bf16_f32 %0, %1, %2" : "=v"(w0) : "v"(p0), "v"(p1));
                asm("v_cvt_pk_bf16_f32 %0, %1, %2" : "=v"(w1) : "v"(p2), "v"(p3));
                w[f * 2] = w0; w[f * 2 + 1] = w1;
            }
            lsum[qi] += ps;
            pa[qi] = __builtin_bit_cast(bf16x8, w);
        }

        // O += P V over own 32-key half (k-slots permuted consistently: c = perm(k))
        __builtin_amdgcn_s_setprio(1);
        #pragma unroll
        for (int df = 0; df < 4; ++df) {
            bf16x8 vf = *(const bf16x8*)&Vp[(df * 16 + l15) * 64 + ((kb0 + l4 * 8) ^ xsw)];
            oacc[0][df] = __builtin_amdgcn_mfma_f32_16x16x32_bf16(pa[0], vf, oacc[0][df], 0, 0, 0);
            oacc[1][df] = __builtin_amdgcn_mfma_f32_16x16x32_bf16(pa[1], vf, oacc[1][df], 0, 0, 0);
        }
        __builtin_amdgcn_s_setprio(0);

        __syncthreads();  // drains own kt+1 loads (flew under compute) + rendezvous
    }

    #pragma unroll
    for (int qi = 0; qi < 2; ++qi) {
        lsum[qi] += __shfl_xor(lsum[qi], 16, 64);
        lsum[qi] += __shfl_xor(lsum[qi], 32, 64);
    }

    __syncthreads();
    if (lane < 16) {
        Lscr[wk][wq][lane] = lsum[0];
        Lscr[wk][wq][16 + lane] = lsum[1];
    }
    if (wk == 1) {
        #pragma unroll
        for (int qi = 0; qi < 2; ++qi)
            #pragma unroll
            for (int df = 0; df < 4; ++df)
                #pragma unroll
                for (int r = 0; r < 4; ++r)
                    Oscr[wq][qi * 16 + l4 * 4 + r][df * 16 + l15] = oacc[qi][df][r];
    }
    __syncthreads();
    if (wk == 0) {
        #pragma unroll
        for (int qi = 0; qi < 2; ++qi) {
            float inv[4];
            #pragma unroll
            for (int r = 0; r < 4; ++r) {
                const int ql = qi * 16 + l4 * 4 + r;
                inv[r] = 1.0f / (Lscr[0][wq][ql] + Lscr[1][wq][ql]);
            }
            #pragma unroll
            for (int r = 0; r < 4; ++r) {
                const int ql = qi * 16 + l4 * 4 + r;
                const int q = qbase + ql;
                #pragma unroll
                for (int df = 0; df < 4; ++df) {
                    const int d = df * 16 + l15;
                    const float v = oacc[qi][df][r] + Oscr[wq][ql][d];
                    Ob[((size_t)(b * 2048 + q)) * 1024 + h * 64 + d] = f2bf(v * inv[r]);
                }
            }
        }
    }
}

// ---------------- launch ----------------
extern "C" void kernel_launch(void* const* d_in, const int* in_sizes, int n_in,
                              void* d_out, int out_size, void* d_ws, size_t ws_size,
                              hipStream_t stream) {
    const float* x      = (const float*)d_in[0];
    const float* abias  = (const float*)d_in[1];
    const float* w_qkv  = (const float*)d_in[2];
    const float* b_qkv  = (const float*)d_in[3];
    const float* w_proj = (const float*)d_in[4];
    const float* b_proj = (const float*)d_in[5];
    float* out = (float*)d_out;

    unsigned short* ws = (unsigned short*)d_ws;
    unsigned short* xb  = ws;                                  // 4096*1024
    unsigned short* wqT = xb  + (size_t)4096 * 1024;           // 3072*1024
    unsigned short* wpT = wqT + (size_t)3072 * 1024;           // 1024*1024
    unsigned short* qb  = wpT + (size_t)1024 * 1024;           // 2*16*2048*64
    unsigned short* kb  = qb  + (size_t)2 * 16 * 2048 * 64;
    unsigned short* vt  = kb  + (size_t)2 * 16 * 2048 * 64;    // V^T perm'd
    unsigned short* ao  = vt  + (size_t)2 * 16 * 2048 * 64;    // 4096*1024

    cvt_f32_bf16<<<4096, 256, 0, stream>>>(x, xb, 1048576);
    transpose_w<<<dim3(48, 16), 256, 0, stream>>>(w_qkv, wqT, 1024, 3072);
    transpose_w<<<dim3(16, 16), 256, 0, stream>>>(w_proj, wpT, 1024, 1024);
    gemm256_qkv<<<192, 512, 0, stream>>>(xb, wqT, b_qkv, qb, kb, vt);
    attn_kernel<<<512, 512, 0, stream>>>(qb, kb, vt, abias, ao);
    gemm_proj<<<dim3(16, 32), 256, 0, stream>>>(ao, wpT, b_proj, out);
}